// Round 1
// baseline (709.997 us; speedup 1.0000x reference)
//
#include <hip/hip_runtime.h>
#include <hip/hip_bf16.h>
#include <stdint.h>

#define M_TOT 8192   // B*S
#define N_TOT 4096   // D_OUT
#define K_TOT 4096   // D_IN

typedef __bf16 bf16x8 __attribute__((ext_vector_type(8)));
typedef float  f32x4  __attribute__((ext_vector_type(4)));

__device__ __forceinline__ uint16_t f2bf_rne(float f) {
  uint32_t u = __float_as_uint(f);
  u += 0x7fffu + ((u >> 16) & 1u);
  return (uint16_t)(u >> 16);
}

// ternary weight: (wp>0) - (wn<=0) in bf16 bits: 1.0=0x3F80, -1.0=0xBF80
__device__ __forceinline__ uint32_t tern(float p, float n) {
  bool pp = p > 0.0f, nn = n > 0.0f;
  return pp ? (nn ? 0x3F80u : 0u) : (nn ? 0u : 0xBF80u);
}

// ---- preprocess 1: x fp32 -> bf16 bits (8 elems/thread) ----
__global__ __launch_bounds__(256) void cast_x_kernel(const float4* __restrict__ x,
                                                     uint4* __restrict__ out) {
  int t = blockIdx.x * 256 + threadIdx.x;
  float4 a = x[2 * t], b = x[2 * t + 1];
  uint4 o;
  o.x = (uint32_t)f2bf_rne(a.x) | ((uint32_t)f2bf_rne(a.y) << 16);
  o.y = (uint32_t)f2bf_rne(a.z) | ((uint32_t)f2bf_rne(a.w) << 16);
  o.z = (uint32_t)f2bf_rne(b.x) | ((uint32_t)f2bf_rne(b.y) << 16);
  o.w = (uint32_t)f2bf_rne(b.z) | ((uint32_t)f2bf_rne(b.w) << 16);
  out[t] = o;
}

// ---- preprocess 2: W = (wp>0)-(wn<=0) as bf16 bits (8 elems/thread) ----
__global__ __launch_bounds__(256) void ternarize_kernel(const float4* __restrict__ wp,
                                                        const float4* __restrict__ wn,
                                                        uint4* __restrict__ out) {
  int t = blockIdx.x * 256 + threadIdx.x;
  float4 p0 = wp[2 * t], p1 = wp[2 * t + 1];
  float4 n0 = wn[2 * t], n1 = wn[2 * t + 1];
  uint4 o;
  o.x = tern(p0.x, n0.x) | (tern(p0.y, n0.y) << 16);
  o.y = tern(p0.z, n0.z) | (tern(p0.w, n0.w) << 16);
  o.z = tern(p1.x, n1.x) | (tern(p1.y, n1.y) << 16);
  o.w = tern(p1.z, n1.z) | (tern(p1.w, n1.w) << 16);
  out[t] = o;
}

// ---- GEMM: C[M,N] = Xb[M,K] * Wb[N,K]^T, bf16 MFMA 16x16x32, 128x128 tile ----
// 256 threads = 4 waves in 2x2; each wave: 4x4 accumulator tiles of 16x16 (64x64).
// LDS: A tile 128x32 bf16 row-major [0,8192), B tile 128x32 bf16 [8192,16384).
// Staged via global_load_lds width=16 (wave-uniform base + lane*16 — no padding).
__global__ __launch_bounds__(256) void gemm_tern_kernel(const uint16_t* __restrict__ Xb,
                                                        const uint16_t* __restrict__ Wb,
                                                        float* __restrict__ C) {
  __shared__ __align__(16) char smem[16384];
  const int tid  = threadIdx.x;
  const int wave = tid >> 6;
  const int lane = tid & 63;
  const int wm   = wave >> 1;
  const int wn   = wave & 1;
  const int bm   = blockIdx.y;
  const int bn   = blockIdx.x;

  // staging: 4 rounds of 256 lanes x 16B = 4KB each; rr<2 -> A, rr>=2 -> B
  const char* src[4];
  char*       dst[4];
#pragma unroll
  for (int rr = 0; rr < 4; ++rr) {
    int o_full = rr * 4096 + wave * 1024 + lane * 16;  // byte offset incl. lane
    dst[rr] = smem + rr * 4096 + wave * 1024;          // wave-uniform LDS base
    if (rr < 2) {
      int row = o_full >> 6, cb = o_full & 63;         // row stride 64B (32 bf16)
      src[rr] = (const char*)Xb + (size_t)(bm * 128 + row) * (K_TOT * 2) + cb;
    } else {
      int o = o_full - 8192;
      int row = o >> 6, cb = o & 63;
      src[rr] = (const char*)Wb + (size_t)(bn * 128 + row) * (K_TOT * 2) + cb;
    }
  }

  const int lh = lane & 15, lq = lane >> 4;
  int aoff[4], boff[4];
#pragma unroll
  for (int i = 0; i < 4; ++i) {
    aoff[i] = (wm * 64 + i * 16 + lh) * 64 + lq * 16;         // A frag: m=lane&15, k=quad*8+j
    boff[i] = 8192 + (wn * 64 + i * 16 + lh) * 64 + lq * 16;  // B frag same pattern
  }

  f32x4 acc[4][4];
#pragma unroll
  for (int i = 0; i < 4; ++i)
#pragma unroll
    for (int j = 0; j < 4; ++j) acc[i][j] = (f32x4){0.f, 0.f, 0.f, 0.f};

  for (int k0 = 0; k0 < K_TOT; k0 += 32) {
#pragma unroll
    for (int rr = 0; rr < 4; ++rr) {
      __builtin_amdgcn_global_load_lds(
          (const __attribute__((address_space(1))) unsigned int*)src[rr],
          (__attribute__((address_space(3))) unsigned int*)dst[rr], 16, 0, 0);
      src[rr] += 64;  // advance K by 32 bf16
    }
    __syncthreads();  // compiler emits vmcnt(0) drain before barrier

    bf16x8 af[4], bfr[4];
#pragma unroll
    for (int i = 0; i < 4; ++i) af[i] = *(const bf16x8*)(smem + aoff[i]);
#pragma unroll
    for (int j = 0; j < 4; ++j) bfr[j] = *(const bf16x8*)(smem + boff[j]);
#pragma unroll
    for (int i = 0; i < 4; ++i)
#pragma unroll
      for (int j = 0; j < 4; ++j)
        acc[i][j] = __builtin_amdgcn_mfma_f32_16x16x32_bf16(af[i], bfr[j], acc[i][j], 0, 0, 0);
    __syncthreads();
  }

  // epilogue: C/D layout col = lane&15, row = quad*4 + reg
  const size_t base_m = (size_t)bm * 128 + wm * 64;
  const size_t base_n = (size_t)bn * 128 + wn * 64;
#pragma unroll
  for (int i = 0; i < 4; ++i) {
#pragma unroll
    for (int j = 0; j < 4; ++j) {
      size_t m0 = base_m + i * 16 + lq * 4;
      size_t n  = base_n + j * 16 + lh;
      float* p = C + m0 * N_TOT + n;
#pragma unroll
      for (int r = 0; r < 4; ++r) p[(size_t)r * N_TOT] = acc[i][j][r];
    }
  }
}

extern "C" void kernel_launch(void* const* d_in, const int* in_sizes, int n_in,
                              void* d_out, int out_size, void* d_ws, size_t ws_size,
                              hipStream_t stream) {
  const float* x  = (const float*)d_in[0];
  const float* wp = (const float*)d_in[1];
  const float* wn = (const float*)d_in[2];
  float* y = (float*)d_out;

  uint16_t* Xb = (uint16_t*)d_ws;                       // 8192*4096 bf16 = 64 MiB
  uint16_t* Wb = Xb + (size_t)M_TOT * K_TOT;            // 4096*4096 bf16 = 32 MiB

  cast_x_kernel<<<(M_TOT * (size_t)K_TOT) / 2048, 256, 0, stream>>>(
      (const float4*)x, (uint4*)Xb);
  ternarize_kernel<<<(N_TOT * (size_t)K_TOT) / 2048, 256, 0, stream>>>(
      (const float4*)wp, (const float4*)wn, (uint4*)Wb);

  dim3 grid(N_TOT / 128, M_TOT / 128);  // 32 x 64 = 2048 blocks
  gemm_tern_kernel<<<grid, 256, 0, stream>>>(Xb, Wb, y);
}

// Round 2
// 703.530 us; speedup vs baseline: 1.0092x; 1.0092x over previous
//
#include <hip/hip_runtime.h>
#include <hip/hip_bf16.h>
#include <stdint.h>

#define M_TOT 8192   // B*S
#define N_TOT 4096   // D_OUT
#define K_TOT 4096   // D_IN

typedef __bf16 bf16x8 __attribute__((ext_vector_type(8)));
typedef float  f32x4  __attribute__((ext_vector_type(4)));

__device__ __forceinline__ uint16_t f2bf_rne(float f) {
  uint32_t u = __float_as_uint(f);
  u += 0x7fffu + ((u >> 16) & 1u);
  return (uint16_t)(u >> 16);
}

// ternary weight: (wp>0) - (wn<=0) in bf16 bits: 1.0=0x3F80, -1.0=0xBF80
__device__ __forceinline__ uint32_t tern(float p, float n) {
  bool pp = p > 0.0f, nn = n > 0.0f;
  return pp ? (nn ? 0x3F80u : 0u) : (nn ? 0u : 0xBF80u);
}

// ---- preprocess 1: x fp32 -> bf16 bits (8 elems/thread) ----
__global__ __launch_bounds__(256) void cast_x_kernel(const float4* __restrict__ x,
                                                     uint4* __restrict__ out) {
  int t = blockIdx.x * 256 + threadIdx.x;
  float4 a = x[2 * t], b = x[2 * t + 1];
  uint4 o;
  o.x = (uint32_t)f2bf_rne(a.x) | ((uint32_t)f2bf_rne(a.y) << 16);
  o.y = (uint32_t)f2bf_rne(a.z) | ((uint32_t)f2bf_rne(a.w) << 16);
  o.z = (uint32_t)f2bf_rne(b.x) | ((uint32_t)f2bf_rne(b.y) << 16);
  o.w = (uint32_t)f2bf_rne(b.z) | ((uint32_t)f2bf_rne(b.w) << 16);
  out[t] = o;
}

// ---- preprocess 2: W = (wp>0)-(wn<=0) as bf16 bits (8 elems/thread) ----
__global__ __launch_bounds__(256) void ternarize_kernel(const float4* __restrict__ wp,
                                                        const float4* __restrict__ wn,
                                                        uint4* __restrict__ out) {
  int t = blockIdx.x * 256 + threadIdx.x;
  float4 p0 = wp[2 * t], p1 = wp[2 * t + 1];
  float4 n0 = wn[2 * t], n1 = wn[2 * t + 1];
  uint4 o;
  o.x = tern(p0.x, n0.x) | (tern(p0.y, n0.y) << 16);
  o.y = tern(p0.z, n0.z) | (tern(p0.w, n0.w) << 16);
  o.z = tern(p1.x, n1.x) | (tern(p1.y, n1.y) << 16);
  o.w = tern(p1.z, n1.z) | (tern(p1.w, n1.w) << 16);
  out[t] = o;
}

// ---- GEMM: C[M,N] = Xb[M,K] * Wb[N,K]^T, bf16 MFMA 16x16x32, 128x128 tile ----
// 256 threads = 4 waves in 2x2; each wave: 4x4 accumulator tiles of 16x16 (64x64).
// LDS: A tile 128x32 bf16 [0,8192), B tile 128x32 bf16 [8192,16384).
// XOR swizzle: logical k-chunk c (16B) of row r stored at physical chunk
// p = c ^ ((r>>1)&3). Staging fetches the permuted global chunk so the DMA's
// fixed lane->LDS mapping lands data at its swizzled slot; fragment reads at
// row*64 + ((lq ^ ((lh>>1)&3))*16) then hit all 32 banks exactly 2-way (free).
__global__ __launch_bounds__(256) void gemm_tern_kernel(const uint16_t* __restrict__ Xb,
                                                        const uint16_t* __restrict__ Wb,
                                                        float* __restrict__ C) {
  __shared__ __align__(16) char smem[16384];
  const int tid  = threadIdx.x;
  const int wave = tid >> 6;
  const int lane = tid & 63;
  const int wm   = wave >> 1;
  const int wn   = wave & 1;
  const int bm   = blockIdx.y;
  const int bn   = blockIdx.x;

  // staging: 4 rounds of 256 lanes x 16B = 4KB each; rr<2 -> A, rr>=2 -> B
  const char* src[4];
  char*       dst[4];
#pragma unroll
  for (int rr = 0; rr < 4; ++rr) {
    int o_full = rr * 4096 + wave * 1024 + lane * 16;  // byte offset incl. lane
    dst[rr] = smem + rr * 4096 + wave * 1024;          // wave-uniform LDS base
    int o   = o_full & 8191;
    int row = o >> 6;                                  // tile row (64B = 32 bf16 / row)
    int p   = (o >> 4) & 3;                            // physical 16B chunk
    int c   = p ^ ((row >> 1) & 3);                    // logical k-chunk stored here
    int cb  = c * 16;
    if (o_full < 8192) {
      src[rr] = (const char*)Xb + (size_t)(bm * 128 + row) * (K_TOT * 2) + cb;
    } else {
      src[rr] = (const char*)Wb + (size_t)(bn * 128 + row) * (K_TOT * 2) + cb;
    }
  }

  const int lh = lane & 15, lq = lane >> 4;
  const int sw = (lh >> 1) & 3;                        // swizzle key: row bits 1-2
  int aoff[4], boff[4];
#pragma unroll
  for (int i = 0; i < 4; ++i) {
    aoff[i] = (wm * 64 + i * 16 + lh) * 64 + ((lq ^ sw) * 16);
    boff[i] = 8192 + (wn * 64 + i * 16 + lh) * 64 + ((lq ^ sw) * 16);
  }

  f32x4 acc[4][4];
#pragma unroll
  for (int i = 0; i < 4; ++i)
#pragma unroll
    for (int j = 0; j < 4; ++j) acc[i][j] = (f32x4){0.f, 0.f, 0.f, 0.f};

  for (int k0 = 0; k0 < K_TOT; k0 += 32) {
#pragma unroll
    for (int rr = 0; rr < 4; ++rr) {
      __builtin_amdgcn_global_load_lds(
          (const __attribute__((address_space(1))) unsigned int*)src[rr],
          (__attribute__((address_space(3))) unsigned int*)dst[rr], 16, 0, 0);
      src[rr] += 64;  // advance K by 32 bf16
    }
    __syncthreads();

    bf16x8 af[4], bfr[4];
#pragma unroll
    for (int i = 0; i < 4; ++i) af[i] = *(const bf16x8*)(smem + aoff[i]);
#pragma unroll
    for (int j = 0; j < 4; ++j) bfr[j] = *(const bf16x8*)(smem + boff[j]);
#pragma unroll
    for (int i = 0; i < 4; ++i)
#pragma unroll
      for (int j = 0; j < 4; ++j)
        acc[i][j] = __builtin_amdgcn_mfma_f32_16x16x32_bf16(af[i], bfr[j], acc[i][j], 0, 0, 0);
    __syncthreads();
  }

  // epilogue: C/D layout col = lane&15, row = quad*4 + reg
  const size_t base_m = (size_t)bm * 128 + wm * 64;
  const size_t base_n = (size_t)bn * 128 + wn * 64;
#pragma unroll
  for (int i = 0; i < 4; ++i) {
#pragma unroll
    for (int j = 0; j < 4; ++j) {
      size_t m0 = base_m + i * 16 + lq * 4;
      size_t n  = base_n + j * 16 + lh;
      float* p = C + m0 * N_TOT + n;
#pragma unroll
      for (int r = 0; r < 4; ++r) p[(size_t)r * N_TOT] = acc[i][j][r];
    }
  }
}

extern "C" void kernel_launch(void* const* d_in, const int* in_sizes, int n_in,
                              void* d_out, int out_size, void* d_ws, size_t ws_size,
                              hipStream_t stream) {
  const float* x  = (const float*)d_in[0];
  const float* wp = (const float*)d_in[1];
  const float* wn = (const float*)d_in[2];
  float* y = (float*)d_out;

  uint16_t* Xb = (uint16_t*)d_ws;                       // 8192*4096 bf16 = 64 MiB
  uint16_t* Wb = Xb + (size_t)M_TOT * K_TOT;            // 4096*4096 bf16 = 32 MiB

  cast_x_kernel<<<(M_TOT * (size_t)K_TOT) / 2048, 256, 0, stream>>>(
      (const float4*)x, (uint4*)Xb);
  ternarize_kernel<<<(N_TOT * (size_t)K_TOT) / 2048, 256, 0, stream>>>(
      (const float4*)wp, (const float4*)wn, (uint4*)Wb);

  dim3 grid(N_TOT / 128, M_TOT / 128);  // 32 x 64 = 2048 blocks
  gemm_tern_kernel<<<grid, 256, 0, stream>>>(Xb, Wb, y);
}